// Round 5
// baseline (301.277 us; speedup 1.0000x reference)
//
#include <hip/hip_runtime.h>
#include <hip/hip_fp16.h>

#define N_NODES 50000
#define N_EDGES 800000
#define FDIM 64
#define N_GRAPHS 500
#define OUTF 10
#define BSHIFT 3
#define BNODES (1 << BSHIFT)                 // 8 nodes per bucket
#define NBUCK (N_NODES >> BSHIFT)            // 6250, exact
#define CSR_CAP (N_EDGES + 8 * N_NODES)
#define SENT N_NODES

struct __align__(8) H4 { __half2 a, b; };

__device__ __forceinline__ float rl(float v, int l) {
    return __int_as_float(__builtin_amdgcn_readlane(__float_as_int(v), l));
}

// ---------------- bucket histogram (+ zero the fp16 sentinel rows) ----------------
__global__ void bucket_count(const int* __restrict__ dst, int* __restrict__ bcount,
                             __half* __restrict__ s0, __half* __restrict__ s1) {
    if (blockIdx.x == 0 && threadIdx.x < 2 * FDIM) {
        __half z = __float2half(0.f);
        if (threadIdx.x < FDIM) s0[threadIdx.x] = z;
        else                    s1[threadIdx.x - FDIM] = z;
    }
    int e = blockIdx.x * blockDim.x + threadIdx.x;
    if (e < N_EDGES) atomicAdd(&bcount[dst[e] >> BSHIFT], 1);
}

// ---------------- bucket region allocation: block scan + 1 atomic/block ----------------
__global__ __launch_bounds__(256) void bucket_alloc(const int* __restrict__ bcount,
                                                    int* __restrict__ bcur,
                                                    int* __restrict__ ecursor) {
    int i = blockIdx.x * 256 + threadIdx.x;
    int c = (i < NBUCK) ? bcount[i] : 0;
    int lane = threadIdx.x & 63, w = threadIdx.x >> 6;
    int v = c;
    #pragma unroll
    for (int off = 1; off < 64; off <<= 1) {
        int t = __shfl_up(v, off);
        if (lane >= off) v += t;
    }
    __shared__ int wsum[4];
    __shared__ int base;
    if (lane == 63) wsum[w] = v;
    __syncthreads();
    if (threadIdx.x == 0) {
        int run = 0;
        #pragma unroll
        for (int k = 0; k < 4; ++k) { int t = wsum[k]; wsum[k] = run; run += t; }
        base = atomicAdd(ecursor, run);
    }
    __syncthreads();
    if (i < NBUCK) bcur[i] = base + wsum[w] + (v - c);
}

// ---------------- edge scatter into bucket regions (dense-line writes) ----------------
__global__ void bucket_scatter(const int* __restrict__ src, const int* __restrict__ dst,
                               int* __restrict__ bcur, int2* __restrict__ ebuf) {
    int e = blockIdx.x * blockDim.x + threadIdx.x;
    if (e >= N_EDGES) return;
    int s = src[e], d = dst[e];
    int pos = atomicAdd(&bcur[d >> BSHIFT], 1);
    ebuf[pos] = make_int2(s, d);
}

// ---------------- per-bucket CSR build: one wave per bucket ----------------
// bcur[b] now = end of bucket region; start = end - bcount[b].
__global__ __launch_bounds__(256) void bucket_build(
    const int* __restrict__ bcur, const int* __restrict__ bcount,
    const int2* __restrict__ ebuf, int2* __restrict__ rowinfo,
    float* __restrict__ dinv, int* __restrict__ cursor, int* __restrict__ csr_src) {
    __shared__ int cnt[4][BNODES], nbase[4][BNODES], nfill[4][BNODES];
    int w = threadIdx.x >> 6, lane = threadIdx.x & 63;
    int b = blockIdx.x * 4 + w;
    if (b >= NBUCK) return;                    // no __syncthreads below: safe
    int n0 = b << BSHIFT;
    int ec = bcount[b];
    int e0 = bcur[b] - ec;
    if (lane < BNODES) { cnt[w][lane] = 0; nfill[w][lane] = 0; }
    for (int i = lane; i < ec; i += 64)
        atomicAdd(&cnt[w][ebuf[e0 + i].y - n0], 1);
    // lanes 0..7: pad, scan, allocate chunk, write rowinfo/dinv/sentinels
    int d = 0, dpad = 0;
    if (lane < BNODES) {
        d = cnt[w][lane];
        dpad = (d + 7) & ~7;
        if (dpad == 0) dpad = 8;               // deg-0 nodes: 8 sentinel slots
    }
    int v = dpad;
    #pragma unroll
    for (int off = 1; off < BNODES; off <<= 1) {
        int t = __shfl_up(v, off);
        if (lane >= off) v += t;
    }
    int total = __shfl(v, BNODES - 1);
    int chunk = 0;
    if (lane == 0) chunk = atomicAdd(cursor, total);
    chunk = __shfl(chunk, 0);
    if (lane < BNODES) {
        int base = chunk + v - dpad;
        nbase[w][lane] = base;
        rowinfo[n0 + lane] = make_int2(base, dpad);
        dinv[n0 + lane] = rsqrtf((float)d + 1.0f);
        for (int k = d; k < dpad; ++k) csr_src[base + k] = SENT;
    }
    // dense fill of this bucket's contiguous CSR chunk
    for (int i = lane; i < ec; i += 64) {
        int2 e = ebuf[e0 + i];
        int li = e.y - n0;
        int pos = nbase[w][li] + atomicAdd(&nfill[w][li], 1);
        csr_src[pos] = e.x;
    }
}

// batch sorted: start[g] = first node with batch >= g
__global__ void seg_starts(const int* __restrict__ batch, int* __restrict__ start) {
    int i = blockIdx.x * blockDim.x + threadIdx.x;
    if (i > N_NODES) return;
    int b  = (i < N_NODES) ? batch[i] : N_GRAPHS;
    int bp = (i == 0) ? -1 : batch[i - 1];
    for (int g = bp + 1; g <= b; ++g) start[g] = i;
}

// hs_x[n] = fp16( dinv[n] * x[n] )
__global__ void prescale(const float* __restrict__ x, const float* __restrict__ dinv,
                         __half* __restrict__ hs) {
    int gid = blockIdx.x * blockDim.x + threadIdx.x;
    if (gid >= N_NODES * 16) return;
    float dn = dinv[gid >> 4];
    float4 v = ((const float4*)x)[gid];
    H4 o;
    o.a = __floats2half2_rn(v.x * dn, v.y * dn);
    o.b = __floats2half2_rn(v.z * dn, v.w * dn);
    ((H4*)hs)[gid] = o;
}

// ---------------- fused GCN layer (fp16 gather, fp32 math) ----------------
template <bool SCALE_OUT, typename OT>
__global__ __launch_bounds__(256) void gcn_fused(
    const int2* __restrict__ rowinfo, const int* __restrict__ csr_src,
    const float* __restrict__ dinv, const __half* __restrict__ hs,
    const float* __restrict__ W, const float* __restrict__ bias,
    OT* __restrict__ out) {
    __shared__ float Ws[FDIM * FDIM];
    int tid = threadIdx.x;
    int lane = tid & 63;
    int L = lane & 15, q = lane >> 4;
    int nodeBase = (blockIdx.x * 4 + (tid >> 6)) * 4;   // grid = 3125 exact
    int myN = nodeBase + q;

    float dn = dinv[myN];
    int2 ri = rowinfo[myN];
    int row = ri.x, dpad = ri.y;
    int rowLast = row + dpad - 1;
    int maxd = dpad;
    maxd = max(maxd, __shfl_xor(maxd, 16));
    maxd = max(maxd, __shfl_xor(maxd, 32));

    H4 sv = *(const H4*)(hs + (size_t)myN * FDIM + 4 * L);  // self term
    float2 slo = __half22float2(sv.a), shi = __half22float2(sv.b);
    float4 acc = make_float4(slo.x, slo.y, shi.x, shi.y);

    #pragma unroll
    for (int i = 0; i < 16; ++i) Ws[tid + i * 256] = W[tid + i * 256];
    __syncthreads();

    for (int base = 0; base < maxd; base += 8) {
        #pragma unroll
        for (int j = 0; j < 8; ++j) {
            int idx = min(row + base + j, rowLast);
            int s = csr_src[idx];
            H4 hv = *(const H4*)(hs + (size_t)s * FDIM + 4 * L);
            float2 lo = __half22float2(hv.a), hi = __half22float2(hv.b);
            acc.x += lo.x; acc.y += lo.y; acc.z += hi.x; acc.w += hi.y;
        }
    }
    acc.x *= dn; acc.y *= dn; acc.z *= dn; acc.w *= dn;

    float b0 = bias[lane];
    float o0 = b0, o1 = b0, o2 = b0, o3 = b0;
    #pragma unroll
    for (int k = 0; k < 64; ++k) {
        float wv = Ws[k * 64 + lane];
        int sl = k >> 2;
        float comp = (k & 3) == 0 ? acc.x : (k & 3) == 1 ? acc.y : (k & 3) == 2 ? acc.z : acc.w;
        o0 = fmaf(rl(comp, sl),      wv, o0);
        o1 = fmaf(rl(comp, sl + 16), wv, o1);
        o2 = fmaf(rl(comp, sl + 32), wv, o2);
        o3 = fmaf(rl(comp, sl + 48), wv, o3);
    }
    o0 = fmaxf(o0, 0.f); o1 = fmaxf(o1, 0.f); o2 = fmaxf(o2, 0.f); o3 = fmaxf(o3, 0.f);
    if (SCALE_OUT) {   // pre-scale rows by dinv for the next layer's gather
        o0 *= rl(dn, 0); o1 *= rl(dn, 16); o2 *= rl(dn, 32); o3 *= rl(dn, 48);
    }
    if constexpr (sizeof(OT) == 2) {
        out[(size_t)(nodeBase + 0) * FDIM + lane] = (OT)__float2half_rn(o0);
        out[(size_t)(nodeBase + 1) * FDIM + lane] = (OT)__float2half_rn(o1);
        out[(size_t)(nodeBase + 2) * FDIM + lane] = (OT)__float2half_rn(o2);
        out[(size_t)(nodeBase + 3) * FDIM + lane] = (OT)__float2half_rn(o3);
    } else {
        out[(size_t)(nodeBase + 0) * FDIM + lane] = o0;
        out[(size_t)(nodeBase + 1) * FDIM + lane] = o1;
        out[(size_t)(nodeBase + 2) * FDIM + lane] = o2;
        out[(size_t)(nodeBase + 3) * FDIM + lane] = o3;
    }
}

// ---------------- fused mean-pool + head + log_softmax ----------------
__global__ __launch_bounds__(256) void pool_head(
    const float* __restrict__ h, const int* __restrict__ start,
    const float* __restrict__ Wc, const float* __restrict__ bc,
    float* __restrict__ out) {
    int g = blockIdx.x;
    int tid = threadIdx.x;
    int lane = tid & 63, w = tid >> 6;
    int L = lane & 15, q = lane >> 4;
    int s0 = start[g], s1 = start[g + 1];
    int sub = w * 4 + q;

    float4 acc = make_float4(0.f, 0.f, 0.f, 0.f);
    for (int i = s0 + sub; i < s1; i += 16) {
        const float4 v = *(const float4*)(h + (size_t)i * FDIM + 4 * L);
        acc.x += v.x; acc.y += v.y; acc.z += v.z; acc.w += v.w;
    }
    #pragma unroll
    for (int m = 16; m <= 32; m <<= 1) {
        acc.x += __shfl_xor(acc.x, m);
        acc.y += __shfl_xor(acc.y, m);
        acc.z += __shfl_xor(acc.z, m);
        acc.w += __shfl_xor(acc.w, m);
    }
    __shared__ float ps[4 * 64];
    __shared__ float pm[64];
    __shared__ float logits[OUTF];
    if (q == 0) *(float4*)(ps + w * 64 + 4 * L) = acc;
    __syncthreads();
    if (tid < 64) {
        float tot = ps[tid] + ps[64 + tid] + ps[128 + tid] + ps[192 + tid];
        float c = (float)((s1 - s0) > 1 ? (s1 - s0) : 1);
        pm[tid] = tot / c;
    }
    __syncthreads();
    if (tid < OUTF) {
        float a = bc[tid];
        #pragma unroll
        for (int k = 0; k < 64; ++k) a = fmaf(pm[k], Wc[k * OUTF + tid], a);
        logits[tid] = a;
    }
    __syncthreads();
    if (tid == 0) {
        float m = -1e30f;
        #pragma unroll
        for (int i = 0; i < OUTF; ++i) m = fmaxf(m, logits[i]);
        float s = 0.f;
        #pragma unroll
        for (int i = 0; i < OUTF; ++i) s += __expf(logits[i] - m);
        float lse = m + __logf(s);
        #pragma unroll
        for (int i = 0; i < OUTF; ++i) out[g * OUTF + i] = logits[i] - lse;
    }
}

extern "C" void kernel_launch(void* const* d_in, const int* in_sizes, int n_in,
                              void* d_out, int out_size, void* d_ws, size_t ws_size,
                              hipStream_t stream) {
    const float* x     = (const float*)d_in[0];
    const int*   ei    = (const int*)d_in[1];
    const int*   batch = (const int*)d_in[2];
    const float* W1    = (const float*)d_in[3];
    const float* b1    = (const float*)d_in[4];
    const float* W2    = (const float*)d_in[5];
    const float* b2    = (const float*)d_in[6];
    const float* Wc    = (const float*)d_in[7];
    const float* bc    = (const float*)d_in[8];
    float* out = (float*)d_out;

    const int* src = ei;
    const int* dst = ei + N_EDGES;

    // workspace layout (int units; alignment: ebuf/out2 16B-aligned)
    int*    ws      = (int*)d_ws;
    int*    bcount  = ws;                               // 6250 } zeroed
    int*    ecursor = bcount + NBUCK;                   // 1    } together
    int*    cursor  = ecursor + 1;                      // 1    } (6252 ints)
    int*    bcur    = cursor + 1;                       // 6250
    int2*   rowinfo = (int2*)(bcur + NBUCK);            // int off 12502 (even) — 50000 int2
    float*  dinv    = (float*)(rowinfo + N_NODES);      // 50000
    int*    start   = (int*)(dinv + N_NODES);           // 504
    int*    csr_src = start + N_GRAPHS + 6;             // int off 163012 (mult 4) — CSR_CAP
    int2*   ebuf    = (int2*)(csr_src + CSR_CAP);       // int off 1363012 (mult 4) — 800000 int2
    __half* hsx     = (__half*)(ebuf + N_EDGES);        // (N_NODES+1)*64 halves
    __half* hs1     = hsx + (size_t)(N_NODES + 1) * FDIM;
    float*  out2    = (float*)ebuf;                     // alias: ebuf+hsx dead after gcn1

    hipMemsetAsync(bcount, 0, (NBUCK + 2) * sizeof(int), stream);

    bucket_count  <<<(N_EDGES + 255) / 256, 256, 0, stream>>>(
        dst, bcount, hsx + (size_t)N_NODES * FDIM, hs1 + (size_t)N_NODES * FDIM);
    bucket_alloc  <<<(NBUCK + 255) / 256, 256, 0, stream>>>(bcount, bcur, ecursor);
    bucket_scatter<<<(N_EDGES + 255) / 256, 256, 0, stream>>>(src, dst, bcur, ebuf);
    bucket_build  <<<(NBUCK + 3) / 4, 256, 0, stream>>>(bcur, bcount, ebuf, rowinfo,
                                                        dinv, cursor, csr_src);
    prescale      <<<(N_NODES * 16 + 255) / 256, 256, 0, stream>>>(x, dinv, hsx);
    seg_starts    <<<(N_NODES + 256) / 256, 256, 0, stream>>>(batch, start);

    const int gcnGrid = N_NODES / 16;  // 3125 exact

    gcn_fused<true,  __half><<<gcnGrid, 256, 0, stream>>>(rowinfo, csr_src, dinv, hsx, W1, b1, hs1);
    gcn_fused<false, float ><<<gcnGrid, 256, 0, stream>>>(rowinfo, csr_src, dinv, hs1, W2, b2, out2);

    pool_head<<<N_GRAPHS, 256, 0, stream>>>(out2, start, Wc, bc, out);
}

// Round 6
// 226.737 us; speedup vs baseline: 1.3288x; 1.3288x over previous
//
#include <hip/hip_runtime.h>
#include <hip/hip_fp16.h>

#define N_NODES 50000
#define N_EDGES 800000
#define FDIM 64
#define N_GRAPHS 500
#define OUTF 10
#define SENT N_NODES

struct __align__(8) H4 { __half2 a, b; };

__device__ __forceinline__ float rl(float v, int l) {
    return __int_as_float(__builtin_amdgcn_readlane(__float_as_int(v), l));
}

// ---------------- degree histogram (+ zero the fp16 sentinel rows) ----------------
__global__ void count_deg(const int* __restrict__ dst, int* __restrict__ deg,
                          __half* __restrict__ s0, __half* __restrict__ s1) {
    if (blockIdx.x == 0 && threadIdx.x < 2 * FDIM) {
        __half z = __float2half(0.f);
        if (threadIdx.x < FDIM) s0[threadIdx.x] = z;
        else                    s1[threadIdx.x - FDIM] = z;
    }
    int e = blockIdx.x * blockDim.x + threadIdx.x;
    if (e < N_EDGES) atomicAdd(&deg[dst[e]], 1);
}

// ---------------- row allocation: block scan + ONE cursor atomic per block ----------------
// rows tightly packed (no sentinel slots). rowinfo = {base, deg}.
__global__ __launch_bounds__(256) void alloc_rows(
    const int* __restrict__ deg, int2* __restrict__ rowinfo,
    float* __restrict__ dinv, int* __restrict__ cursor) {
    int i = blockIdx.x * 256 + threadIdx.x;
    int d = (i < N_NODES) ? deg[i] : 0;
    int lane = threadIdx.x & 63, w = threadIdx.x >> 6;
    int v = d;                               // inclusive wave scan
    #pragma unroll
    for (int off = 1; off < 64; off <<= 1) {
        int t = __shfl_up(v, off);
        if (lane >= off) v += t;
    }
    __shared__ int wsum[4];
    __shared__ int base;
    if (lane == 63) wsum[w] = v;
    __syncthreads();
    if (threadIdx.x == 0) {
        int run = 0;
        #pragma unroll
        for (int k = 0; k < 4; ++k) { int t = wsum[k]; wsum[k] = run; run += t; }
        base = atomicAdd(cursor, run);       // 196 atomics total, order irrelevant
    }
    __syncthreads();
    if (i < N_NODES) {
        rowinfo[i] = make_int2(base + wsum[w] + (v - d), d);
        dinv[i] = rsqrtf((float)d + 1.0f);   // +1 self-loop
    }
}

// ---------------- XCD-affinity CSR fill ----------------
// owner(node) = (n>>5)&7; block's XCD proxy = blockIdx&7 (round-robin dispatch
// heuristic; correctness does NOT depend on it — every edge is processed by
// exactly one block). All stores + fill[] atomics for a row come from one XCD
// -> single L2 copy -> full-line evictions (kills the ~17x write amplification).
__global__ __launch_bounds__(256) void fill_csr_xcd(
    const int* __restrict__ src, const int* __restrict__ dst,
    const int2* __restrict__ rowinfo, int* __restrict__ fill,
    int* __restrict__ csr_src) {
    int myx = blockIdx.x & 7;
    int cid = blockIdx.x >> 3;
    int nch = gridDim.x >> 3;
    for (int e = cid * 256 + threadIdx.x; e < N_EDGES; e += nch * 256) {
        int d = dst[e];
        if (((d >> 5) & 7) != myx) continue;
        int pos = rowinfo[d].x + atomicAdd(&fill[d], 1);
        csr_src[pos] = src[e];
    }
}

// batch sorted: start[g] = first node with batch >= g
__global__ void seg_starts(const int* __restrict__ batch, int* __restrict__ start) {
    int i = blockIdx.x * blockDim.x + threadIdx.x;
    if (i > N_NODES) return;
    int b  = (i < N_NODES) ? batch[i] : N_GRAPHS;
    int bp = (i == 0) ? -1 : batch[i - 1];
    for (int g = bp + 1; g <= b; ++g) start[g] = i;
}

// hs_x[n] = fp16( dinv[n] * x[n] )
__global__ void prescale(const float* __restrict__ x, const float* __restrict__ dinv,
                         __half* __restrict__ hs) {
    int gid = blockIdx.x * blockDim.x + threadIdx.x;
    if (gid >= N_NODES * 16) return;
    float dn = dinv[gid >> 4];
    float4 v = ((const float4*)x)[gid];
    H4 o;
    o.a = __floats2half2_rn(v.x * dn, v.y * dn);
    o.b = __floats2half2_rn(v.z * dn, v.w * dn);
    ((H4*)hs)[gid] = o;
}

// ---------------- fused GCN layer (fp16 gather, fp32 math) ----------------
// one wave = 4 nodes; 16-lane group per node, lane L holds feats [4L..4L+3].
// per-group loop bound (exec-mask divergence is free; masked lanes issue no loads).
template <bool SCALE_OUT, typename OT>
__global__ __launch_bounds__(256) void gcn_fused(
    const int2* __restrict__ rowinfo, const int* __restrict__ csr_src,
    const float* __restrict__ dinv, const __half* __restrict__ hs,
    const float* __restrict__ W, const float* __restrict__ bias,
    OT* __restrict__ out) {
    __shared__ float Ws[FDIM * FDIM];
    int tid = threadIdx.x;
    int lane = tid & 63;
    int L = lane & 15, q = lane >> 4;
    int nodeBase = (blockIdx.x * 4 + (tid >> 6)) * 4;   // grid = 3125 exact
    int myN = nodeBase + q;

    float dn = dinv[myN];
    int2 ri = rowinfo[myN];
    int row = ri.x, d = ri.y;
    int dpad = (d + 7) & ~7;
    int last = row + d - 1;                  // used only when d > 0

    H4 sv = *(const H4*)(hs + (size_t)myN * FDIM + 4 * L);  // self term
    float2 slo = __half22float2(sv.a), shi = __half22float2(sv.b);
    float4 acc = make_float4(slo.x, slo.y, shi.x, shi.y);

    #pragma unroll
    for (int i = 0; i < 16; ++i) Ws[tid + i * 256] = W[tid + i * 256];
    __syncthreads();

    for (int base = 0; base < dpad; base += 8) {
        #pragma unroll
        for (int j = 0; j < 8; ++j) {
            int e = base + j;
            int idx = min(row + e, last);
            int s = csr_src[idx];
            s = (e < d) ? s : SENT;          // tail -> cached zero row
            H4 hv = *(const H4*)(hs + (size_t)s * FDIM + 4 * L);
            float2 lo = __half22float2(hv.a), hi = __half22float2(hv.b);
            acc.x += lo.x; acc.y += lo.y; acc.z += hi.x; acc.w += hi.y;
        }
    }
    acc.x *= dn; acc.y *= dn; acc.z *= dn; acc.w *= dn;

    float b0 = bias[lane];
    float o0 = b0, o1 = b0, o2 = b0, o3 = b0;
    #pragma unroll
    for (int k = 0; k < 64; ++k) {
        float wv = Ws[k * 64 + lane];
        int sl = k >> 2;
        float comp = (k & 3) == 0 ? acc.x : (k & 3) == 1 ? acc.y : (k & 3) == 2 ? acc.z : acc.w;
        o0 = fmaf(rl(comp, sl),      wv, o0);
        o1 = fmaf(rl(comp, sl + 16), wv, o1);
        o2 = fmaf(rl(comp, sl + 32), wv, o2);
        o3 = fmaf(rl(comp, sl + 48), wv, o3);
    }
    o0 = fmaxf(o0, 0.f); o1 = fmaxf(o1, 0.f); o2 = fmaxf(o2, 0.f); o3 = fmaxf(o3, 0.f);
    if (SCALE_OUT) {   // pre-scale rows by dinv for the next layer's gather
        o0 *= rl(dn, 0); o1 *= rl(dn, 16); o2 *= rl(dn, 32); o3 *= rl(dn, 48);
    }
    if constexpr (sizeof(OT) == 2) {
        out[(size_t)(nodeBase + 0) * FDIM + lane] = (OT)__float2half_rn(o0);
        out[(size_t)(nodeBase + 1) * FDIM + lane] = (OT)__float2half_rn(o1);
        out[(size_t)(nodeBase + 2) * FDIM + lane] = (OT)__float2half_rn(o2);
        out[(size_t)(nodeBase + 3) * FDIM + lane] = (OT)__float2half_rn(o3);
    } else {
        out[(size_t)(nodeBase + 0) * FDIM + lane] = o0;
        out[(size_t)(nodeBase + 1) * FDIM + lane] = o1;
        out[(size_t)(nodeBase + 2) * FDIM + lane] = o2;
        out[(size_t)(nodeBase + 3) * FDIM + lane] = o3;
    }
}

// ---------------- fused mean-pool + head + log_softmax ----------------
__global__ __launch_bounds__(256) void pool_head(
    const float* __restrict__ h, const int* __restrict__ start,
    const float* __restrict__ Wc, const float* __restrict__ bc,
    float* __restrict__ out) {
    int g = blockIdx.x;
    int tid = threadIdx.x;
    int lane = tid & 63, w = tid >> 6;
    int L = lane & 15, q = lane >> 4;
    int s0 = start[g], s1 = start[g + 1];
    int sub = w * 4 + q;

    float4 acc = make_float4(0.f, 0.f, 0.f, 0.f);
    for (int i = s0 + sub; i < s1; i += 16) {
        const float4 v = *(const float4*)(h + (size_t)i * FDIM + 4 * L);
        acc.x += v.x; acc.y += v.y; acc.z += v.z; acc.w += v.w;
    }
    #pragma unroll
    for (int m = 16; m <= 32; m <<= 1) {
        acc.x += __shfl_xor(acc.x, m);
        acc.y += __shfl_xor(acc.y, m);
        acc.z += __shfl_xor(acc.z, m);
        acc.w += __shfl_xor(acc.w, m);
    }
    __shared__ float ps[4 * 64];
    __shared__ float pm[64];
    __shared__ float logits[OUTF];
    if (q == 0) *(float4*)(ps + w * 64 + 4 * L) = acc;
    __syncthreads();
    if (tid < 64) {
        float tot = ps[tid] + ps[64 + tid] + ps[128 + tid] + ps[192 + tid];
        float c = (float)((s1 - s0) > 1 ? (s1 - s0) : 1);
        pm[tid] = tot / c;
    }
    __syncthreads();
    if (tid < OUTF) {
        float a = bc[tid];
        #pragma unroll
        for (int k = 0; k < 64; ++k) a = fmaf(pm[k], Wc[k * OUTF + tid], a);
        logits[tid] = a;
    }
    __syncthreads();
    if (tid == 0) {
        float m = -1e30f;
        #pragma unroll
        for (int i = 0; i < OUTF; ++i) m = fmaxf(m, logits[i]);
        float s = 0.f;
        #pragma unroll
        for (int i = 0; i < OUTF; ++i) s += __expf(logits[i] - m);
        float lse = m + __logf(s);
        #pragma unroll
        for (int i = 0; i < OUTF; ++i) out[g * OUTF + i] = logits[i] - lse;
    }
}

extern "C" void kernel_launch(void* const* d_in, const int* in_sizes, int n_in,
                              void* d_out, int out_size, void* d_ws, size_t ws_size,
                              hipStream_t stream) {
    const float* x     = (const float*)d_in[0];
    const int*   ei    = (const int*)d_in[1];
    const int*   batch = (const int*)d_in[2];
    const float* W1    = (const float*)d_in[3];
    const float* b1    = (const float*)d_in[4];
    const float* W2    = (const float*)d_in[5];
    const float* b2    = (const float*)d_in[6];
    const float* Wc    = (const float*)d_in[7];
    const float* bc    = (const float*)d_in[8];
    float* out = (float*)d_out;

    const int* src = ei;
    const int* dst = ei + N_EDGES;

    // workspace layout (int units)
    int*    ws      = (int*)d_ws;
    int*    deg     = ws;                                // 50000 } one
    int*    fill    = deg + N_NODES;                     // 50000 } memset
    int*    cursor  = fill + N_NODES;                    // 1     } (100001 ints)
    int*    pad0    = cursor + 1;                        // 1 (align)
    int2*   rowinfo = (int2*)(pad0 + 1);                 // off 100002 (even) - 50000 int2
    float*  dinv    = (float*)(rowinfo + N_NODES);       // 50000
    int*    start   = (int*)(dinv + N_NODES);            // 504
    int*    csr_src = start + N_GRAPHS + 6;              // N_EDGES + pad
    __half* hsx     = (__half*)(csr_src + N_EDGES + 4);  // (N_NODES+1)*64 halves, 8B-aligned
    __half* hs1     = hsx + (size_t)(N_NODES + 1) * FDIM;
    float*  out2    = (float*)(hs1 + (size_t)(N_NODES + 1) * FDIM);  // 3.2M floats

    hipMemsetAsync(deg, 0, (2 * N_NODES + 1) * sizeof(int), stream);

    count_deg   <<<(N_EDGES + 255) / 256, 256, 0, stream>>>(
        dst, deg, hsx + (size_t)N_NODES * FDIM, hs1 + (size_t)N_NODES * FDIM);
    alloc_rows  <<<(N_NODES + 255) / 256, 256, 0, stream>>>(deg, rowinfo, dinv, cursor);
    fill_csr_xcd<<<2048, 256, 0, stream>>>(src, dst, rowinfo, fill, csr_src);
    prescale    <<<(N_NODES * 16 + 255) / 256, 256, 0, stream>>>(x, dinv, hsx);
    seg_starts  <<<(N_NODES + 256) / 256, 256, 0, stream>>>(batch, start);

    const int gcnGrid = N_NODES / 16;  // 3125 exact

    gcn_fused<true,  __half><<<gcnGrid, 256, 0, stream>>>(rowinfo, csr_src, dinv, hsx, W1, b1, hs1);
    gcn_fused<false, float ><<<gcnGrid, 256, 0, stream>>>(rowinfo, csr_src, dinv, hs1, W2, b2, out2);

    pool_head<<<N_GRAPHS, 256, 0, stream>>>(out2, start, Wc, bc, out);
}